// Round 3
// baseline (752.218 us; speedup 1.0000x reference)
//
#include <hip/hip_runtime.h>
#include <math.h>

typedef unsigned short u16;
typedef __bf16 bf16x8 __attribute__((ext_vector_type(8)));
typedef float  f32x4  __attribute__((ext_vector_type(4)));

__device__ __forceinline__ u16 f2bf(float f) {
    unsigned int u = __float_as_uint(f);
    u = (u + 0x7FFFu + ((u >> 16) & 1u)) >> 16;   // RNE
    return (u16)u;
}

// async global->LDS, 16B/lane; LDS dest must be lane-linear within each wave
__device__ __forceinline__ void gload16(const u16* g, u16* l) {
    __builtin_amdgcn_global_load_lds(
        (const __attribute__((address_space(1))) void*)g,
        (__attribute__((address_space(3))) void*)l, 16, 0, 0);
}

// h-LDS XOR swizzle: element index ^= (row&7)<<3  (byte ^= (row&7)<<4).
// Spreads the per-row 16B granules across the 8 bank clusters; write and
// read use the same involution (h is ds_write/ds_read only - safe).
__device__ __forceinline__ int hswz(int row, int col, int ld) {
    return (row * ld + col) ^ ((row & 7) << 3);
}

// ---------------------------------------------------------------------------
// Merged weight transpose+convert (mode 0: fp32 [G][K][N] -> bf16 [G][N][K])
// and linear fp32->bf16 convert (mode 1, 1024 elems/tile). One launch.
// ---------------------------------------------------------------------------
struct TJob { const float* src; u16* dst; int K, N, tpg, gbase, mode; };
struct TTab { TJob j[16]; };

__global__ void transpose_multi(TTab tab, int njobs) {
    __shared__ u16 tile[32][33];
    int bid = blockIdx.x;
    int ji = 0;
#pragma unroll 1
    for (int t = 1; t < njobs; ++t)
        if (bid >= tab.j[t].gbase) ji = t;
    TJob jb = tab.j[ji];
    int t = bid - jb.gbase;
    if (jb.mode == 1) {                       // linear convert
        long off = (long)t * 1024 + threadIdx.x * 4;
        float4 x = *(const float4*)(jb.src + off);
        ushort4 o;
        o.x = f2bf(x.x); o.y = f2bf(x.y); o.z = f2bf(x.z); o.w = f2bf(x.w);
        *(ushort4*)(jb.dst + off) = o;
        return;
    }
    int g = t / jb.tpg, r = t % jb.tpg;
    int nt = jb.N >> 5;
    int k0 = (r / nt) * 32, n0 = (r % nt) * 32;
    const float* s = jb.src + (long)g * jb.K * jb.N;
    u16* d = jb.dst + (long)g * jb.K * jb.N;
    int tx = threadIdx.x & 31, ty = threadIdx.x >> 5;
#pragma unroll
    for (int rr = ty; rr < 32; rr += 8)
        tile[rr][tx] = f2bf(s[(long)(k0 + rr) * jb.N + n0 + tx]);
    __syncthreads();
#pragma unroll
    for (int rr = ty; rr < 32; rr += 8)
        d[(long)(n0 + rr) * jb.K + k0 + tx] = tile[tx][rr];
}

// ---------------------------------------------------------------------------
// Fused 3-layer FNN chain, hidden width 128 (encoders, head).
// Block = 64 rows x 128 cols, 4 waves (2Mx2N, wave tile 32x64).
// LDS: As 8KB + Bs 16KB + h 16KB = 40KB -> 4 blocks/CU (16 waves/CU).
// grid: (M/64, G), block 256
// ---------------------------------------------------------------------------
__global__ __launch_bounds__(256, 4)
void fnn_chain128(const u16* __restrict__ X, long sXg, int ldx, int K1,
                  const u16* __restrict__ W1t, const float* __restrict__ b1,
                  const u16* __restrict__ Wht, const float* __restrict__ bh,
                  const u16* __restrict__ Wot, const float* __restrict__ bo,
                  int Do, int act3,
                  float* __restrict__ Cf, long sCfg, int ldcf,
                  u16* __restrict__ Cb, long sCbg, int ldcb)
{
    __shared__ __align__(16) u16 As[2][64 * 32];
    __shared__ __align__(16) u16 Bs[2][128 * 32];
    __shared__ __align__(16) u16 h[64 * 128];   // XOR-swizzled

    const int g   = blockIdx.y;
    const int m0  = blockIdx.x * 64;
    const int tid = threadIdx.x;
    const int lane = tid & 63, wv = tid >> 6;
    const int wm = wv & 1, wn = wv >> 1;
    const int lr = lane & 15, lq = lane >> 4;
    const int arow = tid >> 2, akc = (tid & 3) * 8;   // staging granule map

    const u16* a_src = X + (long)g * sXg + (long)(m0 + arow) * ldx + akc;
    const u16* w1r   = W1t + (long)g * 128 * K1 + (long)arow * K1 + akc;
    const u16* whr   = Wht + (long)g * 128 * 128 + (long)arow * 128 + akc;

    const f32x4 z4 = {0.f, 0.f, 0.f, 0.f};
    f32x4 acc[2][4];
#pragma unroll
    for (int i = 0; i < 2; ++i)
#pragma unroll
        for (int j = 0; j < 4; ++j) acc[i][j] = z4;

    // ---------------- L1: X @ W1 (K=K1)
    const int KT1 = K1 >> 5;
    auto stage1 = [&](int buf, int k0) {
        gload16(a_src + k0, &As[buf][arow * 32 + akc]);               // 64x32: 1/thread
        gload16(w1r + k0,                   &Bs[buf][arow * 32 + akc]); // 128x32: 2/thread
        gload16(w1r + (long)64 * K1 + k0,   &Bs[buf][(arow + 64) * 32 + akc]);
    };
    stage1(0, 0);
    __syncthreads();
    for (int kt = 0; kt < KT1; ++kt) {
        int cur = kt & 1;
        if (kt + 1 < KT1) stage1(cur ^ 1, (kt + 1) * 32);
        bf16x8 af[2], bw[4];
#pragma unroll
        for (int i = 0; i < 2; ++i)
            af[i] = *(const bf16x8*)&As[cur][(wm * 32 + i * 16 + lr) * 32 + lq * 8];
#pragma unroll
        for (int j = 0; j < 4; ++j)
            bw[j] = *(const bf16x8*)&Bs[cur][(wn * 64 + j * 16 + lr) * 32 + lq * 8];
#pragma unroll
        for (int i = 0; i < 2; ++i)
#pragma unroll
            for (int j = 0; j < 4; ++j)
                acc[i][j] = __builtin_amdgcn_mfma_f32_16x16x32_bf16(
                    af[i], bw[j], acc[i][j], 0, 0, 0);
        __syncthreads();
    }
    {   // bias + relu -> h (swizzled)
        const float* bg = b1 + (long)g * 128;
#pragma unroll
        for (int j = 0; j < 4; ++j) {
            int n = wn * 64 + j * 16 + lr;
            float bb = bg[n];
#pragma unroll
            for (int i = 0; i < 2; ++i) {
                int mb = wm * 32 + i * 16 + lq * 4;
#pragma unroll
                for (int r = 0; r < 4; ++r)
                    h[hswz(mb + r, n, 128)] = f2bf(fmaxf(acc[i][j][r] + bb, 0.f));
            }
        }
    }

    // ---------------- L2: h @ Wh (K=128)
#pragma unroll
    for (int i = 0; i < 2; ++i)
#pragma unroll
        for (int j = 0; j < 4; ++j) acc[i][j] = z4;
    auto stage2 = [&](int buf, int k0) {
        gload16(whr + k0,                  &Bs[buf][arow * 32 + akc]);
        gload16(whr + (long)64 * 128 + k0, &Bs[buf][(arow + 64) * 32 + akc]);
    };
    stage2(0, 0);
    __syncthreads();
    for (int kt = 0; kt < 4; ++kt) {
        int cur = kt & 1;
        if (kt + 1 < 4) stage2(cur ^ 1, (kt + 1) * 32);
        bf16x8 af[2], bw[4];
#pragma unroll
        for (int i = 0; i < 2; ++i) {
            int row = wm * 32 + i * 16 + lr;
            af[i] = *(const bf16x8*)&h[hswz(row, kt * 32 + lq * 8, 128)];
        }
#pragma unroll
        for (int j = 0; j < 4; ++j)
            bw[j] = *(const bf16x8*)&Bs[cur][(wn * 64 + j * 16 + lr) * 32 + lq * 8];
#pragma unroll
        for (int i = 0; i < 2; ++i)
#pragma unroll
            for (int j = 0; j < 4; ++j)
                acc[i][j] = __builtin_amdgcn_mfma_f32_16x16x32_bf16(
                    af[i], bw[j], acc[i][j], 0, 0, 0);
        __syncthreads();
    }
    {   // bias + relu -> h (in place; all reads drained at final barrier)
        const float* bg = bh + (long)g * 128;
#pragma unroll
        for (int j = 0; j < 4; ++j) {
            int n = wn * 64 + j * 16 + lr;
            float bb = bg[n];
#pragma unroll
            for (int i = 0; i < 2; ++i) {
                int mb = wm * 32 + i * 16 + lq * 4;
#pragma unroll
                for (int r = 0; r < 4; ++r)
                    h[hswz(mb + r, n, 128)] = f2bf(fmaxf(acc[i][j][r] + bb, 0.f));
            }
        }
    }

    // ---------------- L3: h @ Wo (K=128, Do cols)
#pragma unroll
    for (int i = 0; i < 2; ++i)
#pragma unroll
        for (int j = 0; j < 4; ++j) acc[i][j] = z4;
    const int nr0 = (arow < Do) ? arow : Do - 1;          // clamp (Do=32 tail)
    const int nr1 = (arow + 64 < Do) ? arow + 64 : Do - 1;
    const u16* wor0 = Wot + (long)g * Do * 128 + (long)nr0 * 128 + akc;
    const u16* wor1 = Wot + (long)g * Do * 128 + (long)nr1 * 128 + akc;
    auto stage3 = [&](int buf, int k0) {
        gload16(wor0 + k0, &Bs[buf][arow * 32 + akc]);
        gload16(wor1 + k0, &Bs[buf][(arow + 64) * 32 + akc]);
    };
    stage3(0, 0);
    __syncthreads();
    for (int kt = 0; kt < 4; ++kt) {
        int cur = kt & 1;
        if (kt + 1 < 4) stage3(cur ^ 1, (kt + 1) * 32);
        bf16x8 af[2], bw[4];
#pragma unroll
        for (int i = 0; i < 2; ++i) {
            int row = wm * 32 + i * 16 + lr;
            af[i] = *(const bf16x8*)&h[hswz(row, kt * 32 + lq * 8, 128)];
        }
#pragma unroll
        for (int j = 0; j < 4; ++j)
            bw[j] = *(const bf16x8*)&Bs[cur][(wn * 64 + j * 16 + lr) * 32 + lq * 8];
#pragma unroll
        for (int i = 0; i < 2; ++i)
#pragma unroll
            for (int j = 0; j < 4; ++j)
                acc[i][j] = __builtin_amdgcn_mfma_f32_16x16x32_bf16(
                    af[i], bw[j], acc[i][j], 0, 0, 0);
        __syncthreads();
    }
    {   // bias + act3 -> Cf (+Cb mirror)
        const float* bg = bo + (long)g * Do;
#pragma unroll
        for (int j = 0; j < 4; ++j) {
            int n = wn * 64 + j * 16 + lr;
            if (n >= Do) continue;
            float bb = bg[n];
#pragma unroll
            for (int i = 0; i < 2; ++i) {
                int mb = wm * 32 + i * 16 + lq * 4;
#pragma unroll
                for (int r = 0; r < 4; ++r) {
                    float v = acc[i][j][r] + bb;
                    if (act3 == 2) v = tanhf(v);
                    long mrow = m0 + mb + r;
                    Cf[(long)g * sCfg + mrow * ldcf + n] = v;
                    if (Cb) Cb[(long)g * sCbg + mrow * ldcb + n] = f2bf(v);
                }
            }
        }
    }
}

// ---------------------------------------------------------------------------
// Fused 3-layer FNN chain, hidden width 512 (aggregators).
// Block = 32 rows x 512 cols, 4 waves. N handled in two 256-col passes
// (wave tile 32x64 per pass). L2 keeps dual accumulators (one per pass,
// p-loop fully unrolled) so h is read fully before the in-place update.
// LDS: As 4KB + Bs 32KB + h 32KB = 68KB -> 2 blocks/CU.
// W1t/Wht [G][512][512], Wot [G][128][512].
// grid: (M/32, G), block 256
// ---------------------------------------------------------------------------
__global__ __launch_bounds__(256, 2)
void fnn_chain512(const u16* __restrict__ X, long sXg, int ldx,
                  const u16* __restrict__ W1t, const float* __restrict__ b1,
                  const u16* __restrict__ Wht, const float* __restrict__ bh,
                  const u16* __restrict__ Wot, const float* __restrict__ bo,
                  float* __restrict__ Cf, long sCfg, int ldcf,
                  u16* __restrict__ Cb, long sCbg, int ldcb)
{
    __shared__ __align__(16) u16 As[2][32 * 32];    //  4KB
    __shared__ __align__(16) u16 Bs[2][256 * 32];   // 32KB
    __shared__ __align__(16) u16 h[32 * 512];       // 32KB, XOR-swizzled

    const int g   = blockIdx.y;
    const int m0  = blockIdx.x * 32;
    const int tid = threadIdx.x;
    const int lane = tid & 63, wv = tid >> 6;       // wv 0..3
    const int lr = lane & 15, lq = lane >> 4;
    const int arow = tid >> 2, akc = (tid & 3) * 8; // granule map

    const u16* w1g = W1t + (long)g * 512 * 512;
    const u16* whg = Wht + (long)g * 512 * 512;
    const u16* wog = Wot + (long)g * 128 * 512;

    const f32x4 z4 = {0.f, 0.f, 0.f, 0.f};

    // ---------------- L1: X @ W1, two 256-col passes
    auto stageL1 = [&](int buf, int p, int k0) {
        if (tid < 128)                                  // A 32x32: 128 granules
            gload16(X + (long)g * sXg + (long)(m0 + arow) * ldx + akc + k0,
                    &As[buf][arow * 32 + akc]);
        const u16* wb = w1g + (long)(p * 256 + arow) * 512 + akc + k0;
#pragma unroll
        for (int r = 0; r < 4; ++r)                     // B 256x32: 4/thread
            gload16(wb + (long)(64 * r) * 512, &Bs[buf][(r * 64 + arow) * 32 + akc]);
    };
    for (int p = 0; p < 2; ++p) {
        f32x4 acc[2][4];
#pragma unroll
        for (int i = 0; i < 2; ++i)
#pragma unroll
            for (int j = 0; j < 4; ++j) acc[i][j] = z4;
        stageL1(0, p, 0);
        __syncthreads();
        for (int kt = 0; kt < 16; ++kt) {
            int cur = kt & 1;
            if (kt + 1 < 16) stageL1(cur ^ 1, p, (kt + 1) * 32);
            bf16x8 af[2], bw[4];
#pragma unroll
            for (int i = 0; i < 2; ++i)
                af[i] = *(const bf16x8*)&As[cur][(i * 16 + lr) * 32 + lq * 8];
#pragma unroll
            for (int j = 0; j < 4; ++j)
                bw[j] = *(const bf16x8*)&Bs[cur][(wv * 64 + j * 16 + lr) * 32 + lq * 8];
#pragma unroll
            for (int i = 0; i < 2; ++i)
#pragma unroll
                for (int j = 0; j < 4; ++j)
                    acc[i][j] = __builtin_amdgcn_mfma_f32_16x16x32_bf16(
                        af[i], bw[j], acc[i][j], 0, 0, 0);
            __syncthreads();
        }
        const float* bg = b1 + (long)g * 512 + p * 256;
#pragma unroll
        for (int j = 0; j < 4; ++j) {
            int nl = wv * 64 + j * 16 + lr;
            float bb = bg[nl];
#pragma unroll
            for (int i = 0; i < 2; ++i) {
                int mb = i * 16 + lq * 4;
#pragma unroll
                for (int r = 0; r < 4; ++r)
                    h[hswz(mb + r, p * 256 + nl, 512)] =
                        f2bf(fmaxf(acc[i][j][r] + bb, 0.f));
            }
        }
    }

    // ---------------- L2: h @ Wh, dual-acc over the two 256-col passes
    f32x4 acc2[2][2][4];
#pragma unroll
    for (int p = 0; p < 2; ++p)
#pragma unroll
        for (int i = 0; i < 2; ++i)
#pragma unroll
            for (int j = 0; j < 4; ++j) acc2[p][i][j] = z4;
    auto stageL2 = [&](int buf, int p, int k0) {
        const u16* wb = whg + (long)(p * 256 + arow) * 512 + akc + k0;
#pragma unroll
        for (int r = 0; r < 4; ++r)
            gload16(wb + (long)(64 * r) * 512, &Bs[buf][(r * 64 + arow) * 32 + akc]);
    };
    stageL2(0, 0, 0);
    __syncthreads();
#pragma unroll
    for (int p = 0; p < 2; ++p) {
#pragma unroll 1
        for (int kt = 0; kt < 16; ++kt) {
            const int s = p * 16 + kt;
            const int cur = s & 1;
            if (s + 1 < 32) stageL2(cur ^ 1, (s + 1) >> 4, ((s + 1) & 15) * 32);
            bf16x8 af[2], bw[4];
#pragma unroll
            for (int i = 0; i < 2; ++i) {
                int row = i * 16 + lr;
                af[i] = *(const bf16x8*)&h[hswz(row, kt * 32 + lq * 8, 512)];
            }
#pragma unroll
            for (int j = 0; j < 4; ++j)
                bw[j] = *(const bf16x8*)&Bs[cur][(wv * 64 + j * 16 + lr) * 32 + lq * 8];
#pragma unroll
            for (int i = 0; i < 2; ++i)
#pragma unroll
                for (int j = 0; j < 4; ++j)
                    acc2[p][i][j] = __builtin_amdgcn_mfma_f32_16x16x32_bf16(
                        af[i], bw[j], acc2[p][i][j], 0, 0, 0);
            __syncthreads();
        }
    }
    {   // bh + relu -> h in place (all reads complete at last barrier)
        const float* bg = bh + (long)g * 512;
#pragma unroll
        for (int p = 0; p < 2; ++p)
#pragma unroll
            for (int j = 0; j < 4; ++j) {
                int nl = wv * 64 + j * 16 + lr;
                float bb = bg[p * 256 + nl];
#pragma unroll
                for (int i = 0; i < 2; ++i) {
                    int mb = i * 16 + lq * 4;
#pragma unroll
                    for (int r = 0; r < 4; ++r)
                        h[hswz(mb + r, p * 256 + nl, 512)] =
                            f2bf(fmaxf(acc2[p][i][j][r] + bb, 0.f));
                }
            }
    }

    // ---------------- L3: h @ Wo (Do=128, single pass; wave tile 32x32)
    f32x4 acc3[2][2];
#pragma unroll
    for (int i = 0; i < 2; ++i)
#pragma unroll
        for (int j = 0; j < 2; ++j) acc3[i][j] = z4;
    auto stageL3 = [&](int buf, int k0) {
        const u16* wb = wog + (long)arow * 512 + akc + k0;
#pragma unroll
        for (int r = 0; r < 2; ++r)                     // B 128x32: 2/thread
            gload16(wb + (long)(64 * r) * 512, &Bs[buf][(r * 64 + arow) * 32 + akc]);
    };
    stageL3(0, 0);
    __syncthreads();
    for (int kt = 0; kt < 16; ++kt) {
        int cur = kt & 1;
        if (kt + 1 < 16) stageL3(cur ^ 1, (kt + 1) * 32);
        bf16x8 af[2], bw[2];
#pragma unroll
        for (int i = 0; i < 2; ++i) {
            int row = i * 16 + lr;
            af[i] = *(const bf16x8*)&h[hswz(row, kt * 32 + lq * 8, 512)];
        }
#pragma unroll
        for (int j = 0; j < 2; ++j)
            bw[j] = *(const bf16x8*)&Bs[cur][(wv * 32 + j * 16 + lr) * 32 + lq * 8];
#pragma unroll
        for (int i = 0; i < 2; ++i)
#pragma unroll
            for (int j = 0; j < 2; ++j)
                acc3[i][j] = __builtin_amdgcn_mfma_f32_16x16x32_bf16(
                    af[i], bw[j], acc3[i][j], 0, 0, 0);
        __syncthreads();
    }
    {   // bo -> Cf (+Cb mirror)
        const float* bg = bo + (long)g * 128;
#pragma unroll
        for (int j = 0; j < 2; ++j) {
            int n = wv * 32 + j * 16 + lr;
            float bb = bg[n];
#pragma unroll
            for (int i = 0; i < 2; ++i) {
                int mb = i * 16 + lq * 4;
#pragma unroll
                for (int r = 0; r < 4; ++r) {
                    float v = acc3[i][j][r] + bb;
                    long mrow = m0 + mb + r;
                    Cf[(long)g * sCfg + mrow * ldcf + n] = v;
                    if (Cb) Cb[(long)g * sCbg + mrow * ldcb + n] = f2bf(v);
                }
            }
        }
    }
}

// ---------------------------------------------------------------------------
extern "C" void kernel_launch(void* const* d_in, const int* in_sizes, int n_in,
                              void* d_out, int out_size, void* d_ws, size_t ws_size,
                              hipStream_t stream) {
    const int B = 4096, S = 256, D = 128, NA = 32, CD = 512;

    const float* state   = (const float*)d_in[0];
    const float* enc_w1  = (const float*)d_in[1];
    const float* enc_b1  = (const float*)d_in[2];
    const float* enc_wh  = (const float*)d_in[3];
    const float* enc_bh  = (const float*)d_in[4];
    const float* enc_wo  = (const float*)d_in[5];
    const float* enc_bo  = (const float*)d_in[6];
    const float *agg_w1[3], *agg_b1[3], *agg_wh[3], *agg_bh[3], *agg_wo[3], *agg_bo[3];
    for (int l = 0; l < 3; ++l) {
        agg_w1[l] = (const float*)d_in[7 + 6 * l + 0];
        agg_b1[l] = (const float*)d_in[7 + 6 * l + 1];
        agg_wh[l] = (const float*)d_in[7 + 6 * l + 2];
        agg_bh[l] = (const float*)d_in[7 + 6 * l + 3];
        agg_wo[l] = (const float*)d_in[7 + 6 * l + 4];
        agg_bo[l] = (const float*)d_in[7 + 6 * l + 5];
    }
    const float* head_w1 = (const float*)d_in[25];
    const float* head_b1 = (const float*)d_in[26];
    const float* head_wh = (const float*)d_in[27];
    const float* head_bh = (const float*)d_in[28];
    const float* head_wo = (const float*)d_in[29];
    const float* head_bo = (const float*)d_in[30];

    float* out    = (float*)d_out;               // embeds [B][85][128] fp32
    float* action = out + (long)B * 85 * D;      // [B][32] fp32

    // ---- carve workspace (bf16 elements)
    char* wsp = (char*)d_ws;
    auto carve = [&](long elems) {
        u16* p = (u16*)wsp;
        wsp += ((elems * 2 + 255) / 256) * 256;
        return p;
    };
    u16* enc_w1t = carve(64L * 128 * 256);
    u16* enc_wht = carve(64L * 128 * 128);
    u16* enc_wot = carve(64L * 128 * 128);
    u16 *agg_w1t[3], *agg_wht[3], *agg_wot[3];
    const int LN[3] = {16, 4, 1};
    for (int l = 0; l < 3; ++l) {
        agg_w1t[l] = carve((long)LN[l] * 512 * 512);
        agg_wht[l] = carve((long)LN[l] * 512 * 512);
        agg_wot[l] = carve((long)LN[l] * 128 * 512);
    }
    u16* head_w1t = carve(128L * 128);
    u16* head_wht = carve(128L * 128);
    u16* head_wot = carve(32L * 128);
    u16* stateB = carve((long)B * S);            // bf16 state
    u16* bufA   = carve(33554432L);              // bf16 activation mirrors
    u16* bufB   = carve(33554432L);

    // ---- build merged transpose/convert table (one launch)
    TTab tab = {};
    int nj = 0, base = 0;
    auto addT = [&](const float* s, u16* d, int G, int K, int N) {
        int tpg = (K / 32) * (N / 32);
        tab.j[nj] = {s, d, K, N, tpg, base, 0};
        base += G * tpg; ++nj;
    };
    auto addC = [&](const float* s, u16* d, long elems) {
        tab.j[nj] = {s, d, 0, 0, 0, base, 1};
        base += (int)(elems / 1024); ++nj;
    };
    addT(enc_w1, enc_w1t, 64, 256, 128);
    addT(enc_wh, enc_wht, 64, 128, 128);
    addT(enc_wo, enc_wot, 64, 128, 128);
    for (int l = 0; l < 3; ++l) {
        addT(agg_w1[l], agg_w1t[l], LN[l], 512, 512);
        addT(agg_wh[l], agg_wht[l], LN[l], 512, 512);
        addT(agg_wo[l], agg_wot[l], LN[l], 512, 128);
    }
    addT(head_w1, head_w1t, 1, 128, 128);
    addT(head_wh, head_wht, 1, 128, 128);
    addT(head_wo, head_wot, 1, 128, 32);
    addC(state, stateB, (long)B * S);
    transpose_multi<<<base, 256, 0, stream>>>(tab, nj);

    const int LD = 85 * D;   // 10880

    // encoders: fused chain, out fp32 embeds[:,0:64,:] + bf16 mirror [B][64D]
    fnn_chain128<<<dim3(64, 64), 256, 0, stream>>>(
        stateB, 0, S, 256,
        enc_w1t, enc_b1, enc_wht, enc_bh, enc_wot, enc_bo, 128, 0,
        out, D, LD, bufA, D, 64 * D);

    // agg level 0: X = enc mirror [B][64D]; out t=64.. + mirror [B][16D]
    fnn_chain512<<<dim3(128, 16), 256, 0, stream>>>(
        bufA, 512, 64 * D,
        agg_w1t[0], agg_b1[0], agg_wht[0], agg_bh[0], agg_wot[0], agg_bo[0],
        out + 64L * D, D, LD, bufB, D, 16 * D);

    // agg level 1: X = [B][16D]; out t=80.. + mirror [B][4D]
    fnn_chain512<<<dim3(128, 4), 256, 0, stream>>>(
        bufB, 512, 16 * D,
        agg_w1t[1], agg_b1[1], agg_wht[1], agg_bh[1], agg_wot[1], agg_bo[1],
        out + 80L * D, D, LD, bufA, D, 4 * D);

    // agg level 2 (root): X = [B][4D]; out t=84 + mirror [B][D]
    fnn_chain512<<<dim3(128, 1), 256, 0, stream>>>(
        bufA, 0, 4 * D,
        agg_w1t[2], agg_b1[2], agg_wht[2], agg_bh[2], agg_wot[2], agg_bo[2],
        out + 84L * D, D, LD, bufB, 0, D);

    // head: fused chain, X = root mirror [B][D], tanh, Do=32
    fnn_chain128<<<dim3(64, 1), 256, 0, stream>>>(
        bufB, 0, D, 128,
        head_w1t, head_b1, head_wht, head_bh, head_wot, head_bo, 32, 2,
        action, 0, NA, nullptr, 0, 0);
}

// Round 4
// 648.192 us; speedup vs baseline: 1.1605x; 1.1605x over previous
//
#include <hip/hip_runtime.h>
#include <math.h>

typedef unsigned short u16;
typedef __bf16 bf16x8 __attribute__((ext_vector_type(8)));
typedef float  f32x4  __attribute__((ext_vector_type(4)));

__device__ __forceinline__ u16 f2bf(float f) {
    unsigned int u = __float_as_uint(f);
    u = (u + 0x7FFFu + ((u >> 16) & 1u)) >> 16;   // RNE
    return (u16)u;
}

// async global->LDS, 16B/lane; LDS dest must be lane-linear within each wave
__device__ __forceinline__ void gload16(const u16* g, u16* l) {
    __builtin_amdgcn_global_load_lds(
        (const __attribute__((address_space(1))) void*)g,
        (__attribute__((address_space(3))) void*)l, 16, 0, 0);
}

// h-LDS XOR swizzle (chain128 only): element index ^= (row&7)<<3.
__device__ __forceinline__ int hswz(int row, int col, int ld) {
    return (row * ld + col) ^ ((row & 7) << 3);
}

// XCD-pinned block decode: consecutive flat blockIdx round-robin the 8 XCDs,
// so fixing g per (bid&7) makes each group's weights L2-resident on one XCD.
// Bijective for n_g multiple of 8 (branch 1) or divisor of 8 (branch 2).
__device__ __forceinline__ void xcd_decode(int bid, int n_g, int& mb, int& g) {
    int xcd = bid & 7, j = bid >> 3;
    if (n_g >= 8) {
        int gpx = n_g >> 3;                 // groups per XCD
        g  = xcd * gpx + (j % gpx);
        mb = j / gpx;
    } else {
        int xpg = 8 / n_g;                  // XCDs per group
        g  = xcd / xpg;
        mb = j * xpg + (xcd % xpg);
    }
}

// ---------------------------------------------------------------------------
// Merged weight transpose+convert (mode 0: fp32 [G][K][N] -> bf16 [G][N][K])
// and linear fp32->bf16 convert (mode 1, 1024 elems/tile). One launch.
// ---------------------------------------------------------------------------
struct TJob { const float* src; u16* dst; int K, N, tpg, gbase, mode; };
struct TTab { TJob j[16]; };

__global__ void transpose_multi(TTab tab, int njobs) {
    __shared__ u16 tile[32][33];
    int bid = blockIdx.x;
    int ji = 0;
#pragma unroll 1
    for (int t = 1; t < njobs; ++t)
        if (bid >= tab.j[t].gbase) ji = t;
    TJob jb = tab.j[ji];
    int t = bid - jb.gbase;
    if (jb.mode == 1) {                       // linear convert
        long off = (long)t * 1024 + threadIdx.x * 4;
        float4 x = *(const float4*)(jb.src + off);
        ushort4 o;
        o.x = f2bf(x.x); o.y = f2bf(x.y); o.z = f2bf(x.z); o.w = f2bf(x.w);
        *(ushort4*)(jb.dst + off) = o;
        return;
    }
    int g = t / jb.tpg, r = t % jb.tpg;
    int nt = jb.N >> 5;
    int k0 = (r / nt) * 32, n0 = (r % nt) * 32;
    const float* s = jb.src + (long)g * jb.K * jb.N;
    u16* d = jb.dst + (long)g * jb.K * jb.N;
    int tx = threadIdx.x & 31, ty = threadIdx.x >> 5;
#pragma unroll
    for (int rr = ty; rr < 32; rr += 8)
        tile[rr][tx] = f2bf(s[(long)(k0 + rr) * jb.N + n0 + tx]);
    __syncthreads();
#pragma unroll
    for (int rr = ty; rr < 32; rr += 8)
        d[(long)(n0 + rr) * jb.K + k0 + tx] = tile[tx][rr];
}

// ---------------------------------------------------------------------------
// Fused 3-layer FNN chain, hidden width 128 (encoders, head).
// Block = 64 rows x 128 cols, 4 waves (2Mx2N, wave tile 32x64).
// LDS: As 8KB + Bs 16KB + h 16KB = 40KB -> 4 blocks/CU (16 waves/CU).
// grid: 1-D (n_mb * n_g), XCD-pinned decode.
// ---------------------------------------------------------------------------
__global__ __launch_bounds__(256, 4)
void fnn_chain128(int n_g,
                  const u16* __restrict__ X, long sXg, int ldx, int K1,
                  const u16* __restrict__ W1t, const float* __restrict__ b1,
                  const u16* __restrict__ Wht, const float* __restrict__ bh,
                  const u16* __restrict__ Wot, const float* __restrict__ bo,
                  int Do, int act3,
                  float* __restrict__ Cf, long sCfg, int ldcf,
                  u16* __restrict__ Cb, long sCbg, int ldcb)
{
    __shared__ __align__(16) u16 As[2][64 * 32];
    __shared__ __align__(16) u16 Bs[2][128 * 32];
    __shared__ __align__(16) u16 h[64 * 128];   // XOR-swizzled

    int mb, g;
    xcd_decode(blockIdx.x, n_g, mb, g);
    const int m0  = mb * 64;
    const int tid = threadIdx.x;
    const int lane = tid & 63, wv = tid >> 6;
    const int wm = wv & 1, wn = wv >> 1;
    const int lr = lane & 15, lq = lane >> 4;
    const int arow = tid >> 2, akc = (tid & 3) * 8;   // staging granule map

    const u16* a_src = X + (long)g * sXg + (long)(m0 + arow) * ldx + akc;
    const u16* w1r   = W1t + (long)g * 128 * K1 + (long)arow * K1 + akc;
    const u16* whr   = Wht + (long)g * 128 * 128 + (long)arow * 128 + akc;

    const f32x4 z4 = {0.f, 0.f, 0.f, 0.f};
    f32x4 acc[2][4];
#pragma unroll
    for (int i = 0; i < 2; ++i)
#pragma unroll
        for (int j = 0; j < 4; ++j) acc[i][j] = z4;

    // ---------------- L1: X @ W1 (K=K1)
    const int KT1 = K1 >> 5;
    auto stage1 = [&](int buf, int k0) {
        gload16(a_src + k0, &As[buf][arow * 32 + akc]);
        gload16(w1r + k0,                   &Bs[buf][arow * 32 + akc]);
        gload16(w1r + (long)64 * K1 + k0,   &Bs[buf][(arow + 64) * 32 + akc]);
    };
    stage1(0, 0);
    __syncthreads();
    for (int kt = 0; kt < KT1; ++kt) {
        int cur = kt & 1;
        if (kt + 1 < KT1) stage1(cur ^ 1, (kt + 1) * 32);
        bf16x8 af[2], bw[4];
#pragma unroll
        for (int i = 0; i < 2; ++i)
            af[i] = *(const bf16x8*)&As[cur][(wm * 32 + i * 16 + lr) * 32 + lq * 8];
#pragma unroll
        for (int j = 0; j < 4; ++j)
            bw[j] = *(const bf16x8*)&Bs[cur][(wn * 64 + j * 16 + lr) * 32 + lq * 8];
#pragma unroll
        for (int i = 0; i < 2; ++i)
#pragma unroll
            for (int j = 0; j < 4; ++j)
                acc[i][j] = __builtin_amdgcn_mfma_f32_16x16x32_bf16(
                    af[i], bw[j], acc[i][j], 0, 0, 0);
        __syncthreads();
    }
    {   // bias + relu -> h (swizzled)
        const float* bg = b1 + (long)g * 128;
#pragma unroll
        for (int j = 0; j < 4; ++j) {
            int n = wn * 64 + j * 16 + lr;
            float bb = bg[n];
#pragma unroll
            for (int i = 0; i < 2; ++i) {
                int mb2 = wm * 32 + i * 16 + lq * 4;
#pragma unroll
                for (int r = 0; r < 4; ++r)
                    h[hswz(mb2 + r, n, 128)] = f2bf(fmaxf(acc[i][j][r] + bb, 0.f));
            }
        }
    }

    // ---------------- L2: h @ Wh (K=128)
#pragma unroll
    for (int i = 0; i < 2; ++i)
#pragma unroll
        for (int j = 0; j < 4; ++j) acc[i][j] = z4;
    auto stage2 = [&](int buf, int k0) {
        gload16(whr + k0,                  &Bs[buf][arow * 32 + akc]);
        gload16(whr + (long)64 * 128 + k0, &Bs[buf][(arow + 64) * 32 + akc]);
    };
    stage2(0, 0);
    __syncthreads();
    for (int kt = 0; kt < 4; ++kt) {
        int cur = kt & 1;
        if (kt + 1 < 4) stage2(cur ^ 1, (kt + 1) * 32);
        bf16x8 af[2], bw[4];
#pragma unroll
        for (int i = 0; i < 2; ++i) {
            int row = wm * 32 + i * 16 + lr;
            af[i] = *(const bf16x8*)&h[hswz(row, kt * 32 + lq * 8, 128)];
        }
#pragma unroll
        for (int j = 0; j < 4; ++j)
            bw[j] = *(const bf16x8*)&Bs[cur][(wn * 64 + j * 16 + lr) * 32 + lq * 8];
#pragma unroll
        for (int i = 0; i < 2; ++i)
#pragma unroll
            for (int j = 0; j < 4; ++j)
                acc[i][j] = __builtin_amdgcn_mfma_f32_16x16x32_bf16(
                    af[i], bw[j], acc[i][j], 0, 0, 0);
        __syncthreads();
    }
    {   // bias + relu -> h (in place; all reads drained at final barrier)
        const float* bg = bh + (long)g * 128;
#pragma unroll
        for (int j = 0; j < 4; ++j) {
            int n = wn * 64 + j * 16 + lr;
            float bb = bg[n];
#pragma unroll
            for (int i = 0; i < 2; ++i) {
                int mb2 = wm * 32 + i * 16 + lq * 4;
#pragma unroll
                for (int r = 0; r < 4; ++r)
                    h[hswz(mb2 + r, n, 128)] = f2bf(fmaxf(acc[i][j][r] + bb, 0.f));
            }
        }
    }

    // ---------------- L3: h @ Wo (K=128, Do cols)
#pragma unroll
    for (int i = 0; i < 2; ++i)
#pragma unroll
        for (int j = 0; j < 4; ++j) acc[i][j] = z4;
    const int nr0 = (arow < Do) ? arow : Do - 1;          // clamp (Do=32 tail)
    const int nr1 = (arow + 64 < Do) ? arow + 64 : Do - 1;
    const u16* wor0 = Wot + (long)g * Do * 128 + (long)nr0 * 128 + akc;
    const u16* wor1 = Wot + (long)g * Do * 128 + (long)nr1 * 128 + akc;
    auto stage3 = [&](int buf, int k0) {
        gload16(wor0 + k0, &Bs[buf][arow * 32 + akc]);
        gload16(wor1 + k0, &Bs[buf][(arow + 64) * 32 + akc]);
    };
    stage3(0, 0);
    __syncthreads();
    for (int kt = 0; kt < 4; ++kt) {
        int cur = kt & 1;
        if (kt + 1 < 4) stage3(cur ^ 1, (kt + 1) * 32);
        bf16x8 af[2], bw[4];
#pragma unroll
        for (int i = 0; i < 2; ++i) {
            int row = wm * 32 + i * 16 + lr;
            af[i] = *(const bf16x8*)&h[hswz(row, kt * 32 + lq * 8, 128)];
        }
#pragma unroll
        for (int j = 0; j < 4; ++j)
            bw[j] = *(const bf16x8*)&Bs[cur][(wn * 64 + j * 16 + lr) * 32 + lq * 8];
#pragma unroll
        for (int i = 0; i < 2; ++i)
#pragma unroll
            for (int j = 0; j < 4; ++j)
                acc[i][j] = __builtin_amdgcn_mfma_f32_16x16x32_bf16(
                    af[i], bw[j], acc[i][j], 0, 0, 0);
        __syncthreads();
    }
    {   // bias + act3 -> Cf (+Cb mirror)
        const float* bg = bo + (long)g * Do;
#pragma unroll
        for (int j = 0; j < 4; ++j) {
            int n = wn * 64 + j * 16 + lr;
            if (n >= Do) continue;
            float bb = bg[n];
#pragma unroll
            for (int i = 0; i < 2; ++i) {
                int mb2 = wm * 32 + i * 16 + lq * 4;
#pragma unroll
                for (int r = 0; r < 4; ++r) {
                    float v = acc[i][j][r] + bb;
                    if (act3 == 2) v = tanhf(v);
                    long mrow = m0 + mb2 + r;
                    Cf[(long)g * sCfg + mrow * ldcf + n] = v;
                    if (Cb) Cb[(long)g * sCbg + mrow * ldcb + n] = f2bf(v);
                }
            }
        }
    }
}

// ---------------------------------------------------------------------------
// Fused 3-layer FNN chain, hidden width 512 (aggregators). K=512 all layers.
// Block = 64 rows x 512 cols, 8 waves (R2 geometry: wave tile 64x64 for
// L1/L2 = 16 MFMA/wave/K-step). h[64][536] in LDS. LDS 139KB -> 1 block/CU.
// W1t/Wht [G][512][512], Wot [G][128][512].
// grid: 1-D (n_mb * n_g), XCD-pinned decode (weights L2-resident per XCD).
// ---------------------------------------------------------------------------
__global__ __launch_bounds__(512, 2)
void fnn_chain512(int n_g,
                  const u16* __restrict__ X, long sXg, int ldx,
                  const u16* __restrict__ W1t, const float* __restrict__ b1,
                  const u16* __restrict__ Wht, const float* __restrict__ bh,
                  const u16* __restrict__ Wot, const float* __restrict__ bo,
                  float* __restrict__ Cf, long sCfg, int ldcf,
                  u16* __restrict__ Cb, long sCbg, int ldcb)
{
    __shared__ __align__(16) u16 As[2][64 * 32];
    __shared__ __align__(16) u16 Bs[2][512 * 32];
    __shared__ __align__(16) u16 h[64 * 536];

    int mb, g;
    xcd_decode(blockIdx.x, n_g, mb, g);
    const int m0  = mb * 64;
    const int tid = threadIdx.x;
    const int lane = tid & 63, wv = tid >> 6;     // wv 0..7
    const int lr = lane & 15, lq = lane >> 4;
    const int row0 = tid >> 2, c8 = (tid & 3) * 8;  // row0 0..127

    const u16* a_src = X + (long)g * sXg + (long)(m0 + row0) * ldx + c8; // used tid<256
    const u16* w1r = W1t + (long)g * 512 * 512 + (long)row0 * 512 + c8;
    const u16* whr = Wht + (long)g * 512 * 512 + (long)row0 * 512 + c8;
    const u16* wor = Wot + (long)g * 128 * 512 + (long)row0 * 512 + c8;

    const f32x4 z4 = {0.f, 0.f, 0.f, 0.f};
    f32x4 acc[4][4];
#pragma unroll
    for (int i = 0; i < 4; ++i)
#pragma unroll
        for (int j = 0; j < 4; ++j) acc[i][j] = z4;

    // ---------------- L1: X @ W1  (K=512, 16 steps)
    auto stage1 = [&](int buf, int k0) {
        if (tid < 256) gload16(a_src + k0, &As[buf][row0 * 32 + c8]);
#pragma unroll
        for (int r = 0; r < 4; ++r)
            gload16(w1r + (long)(128 * r) * 512 + k0,
                    &Bs[buf][(row0 + 128 * r) * 32 + c8]);
    };
    stage1(0, 0);
    __syncthreads();
    for (int kt = 0; kt < 16; ++kt) {
        int cur = kt & 1;
        if (kt + 1 < 16) stage1(cur ^ 1, (kt + 1) * 32);
        bf16x8 af[4], bw[4];
#pragma unroll
        for (int i = 0; i < 4; ++i)
            af[i] = *(const bf16x8*)&As[cur][(i * 16 + lr) * 32 + lq * 8];
#pragma unroll
        for (int j = 0; j < 4; ++j)
            bw[j] = *(const bf16x8*)&Bs[cur][(wv * 64 + j * 16 + lr) * 32 + lq * 8];
#pragma unroll
        for (int i = 0; i < 4; ++i)
#pragma unroll
            for (int j = 0; j < 4; ++j)
                acc[i][j] = __builtin_amdgcn_mfma_f32_16x16x32_bf16(
                    af[i], bw[j], acc[i][j], 0, 0, 0);
        __syncthreads();
    }
    {   // b1 + relu -> h
        const float* bg = b1 + (long)g * 512;
#pragma unroll
        for (int j = 0; j < 4; ++j) {
            int n = wv * 64 + j * 16 + lr;
            float bb = bg[n];
#pragma unroll
            for (int i = 0; i < 4; ++i) {
                int mb2 = i * 16 + lq * 4;
#pragma unroll
                for (int r = 0; r < 4; ++r)
                    h[(mb2 + r) * 536 + n] = f2bf(fmaxf(acc[i][j][r] + bb, 0.f));
            }
        }
    }

    // ---------------- L2: h @ Wh (K=512)
#pragma unroll
    for (int i = 0; i < 4; ++i)
#pragma unroll
        for (int j = 0; j < 4; ++j) acc[i][j] = z4;
    auto stage2 = [&](int buf, int k0) {
#pragma unroll
        for (int r = 0; r < 4; ++r)
            gload16(whr + (long)(128 * r) * 512 + k0,
                    &Bs[buf][(row0 + 128 * r) * 32 + c8]);
    };
    stage2(0, 0);
    __syncthreads();
    for (int kt = 0; kt < 16; ++kt) {
        int cur = kt & 1;
        if (kt + 1 < 16) stage2(cur ^ 1, (kt + 1) * 32);
        bf16x8 af[4], bw[4];
#pragma unroll
        for (int i = 0; i < 4; ++i)
            af[i] = *(const bf16x8*)&h[(i * 16 + lr) * 536 + kt * 32 + lq * 8];
#pragma unroll
        for (int j = 0; j < 4; ++j)
            bw[j] = *(const bf16x8*)&Bs[cur][(wv * 64 + j * 16 + lr) * 32 + lq * 8];
#pragma unroll
        for (int i = 0; i < 4; ++i)
#pragma unroll
            for (int j = 0; j < 4; ++j)
                acc[i][j] = __builtin_amdgcn_mfma_f32_16x16x32_bf16(
                    af[i], bw[j], acc[i][j], 0, 0, 0);
        __syncthreads();
    }
    {   // bh + relu -> h (in place)
        const float* bg = bh + (long)g * 512;
#pragma unroll
        for (int j = 0; j < 4; ++j) {
            int n = wv * 64 + j * 16 + lr;
            float bb = bg[n];
#pragma unroll
            for (int i = 0; i < 4; ++i) {
                int mb2 = i * 16 + lq * 4;
#pragma unroll
                for (int r = 0; r < 4; ++r)
                    h[(mb2 + r) * 536 + n] = f2bf(fmaxf(acc[i][j][r] + bb, 0.f));
            }
        }
    }

    // ---------------- L3: h @ Wo (K=512, Do=128); 8 waves = 2Mx4N
    const int wm3 = wv & 1, wn3 = wv >> 1;   // wn3 0..3
    f32x4 a2[2][2];
#pragma unroll
    for (int i = 0; i < 2; ++i)
#pragma unroll
        for (int j = 0; j < 2; ++j) a2[i][j] = z4;
    auto stage3 = [&](int buf, int k0) {
        gload16(wor + k0, &Bs[buf][row0 * 32 + c8]);   // 128 rows, one granule
    };
    stage3(0, 0);
    __syncthreads();
    for (int kt = 0; kt < 16; ++kt) {
        int cur = kt & 1;
        if (kt + 1 < 16) stage3(cur ^ 1, (kt + 1) * 32);
        bf16x8 af2[2], bw2[2];
#pragma unroll
        for (int i = 0; i < 2; ++i)
            af2[i] = *(const bf16x8*)&h[(wm3 * 32 + i * 16 + lr) * 536 + kt * 32 + lq * 8];
#pragma unroll
        for (int j = 0; j < 2; ++j)
            bw2[j] = *(const bf16x8*)&Bs[cur][(wn3 * 32 + j * 16 + lr) * 32 + lq * 8];
#pragma unroll
        for (int i = 0; i < 2; ++i)
#pragma unroll
            for (int j = 0; j < 2; ++j)
                a2[i][j] = __builtin_amdgcn_mfma_f32_16x16x32_bf16(
                    af2[i], bw2[j], a2[i][j], 0, 0, 0);
        __syncthreads();
    }
    {   // bo -> Cf (+Cb mirror), no activation
        const float* bg = bo + (long)g * 128;
#pragma unroll
        for (int j = 0; j < 2; ++j) {
            int n = wn3 * 32 + j * 16 + lr;
            float bb = bg[n];
#pragma unroll
            for (int i = 0; i < 2; ++i) {
                int mb2 = wm3 * 32 + i * 16 + lq * 4;
#pragma unroll
                for (int r = 0; r < 4; ++r) {
                    float v = a2[i][j][r] + bb;
                    long mrow = m0 + mb2 + r;
                    Cf[(long)g * sCfg + mrow * ldcf + n] = v;
                    if (Cb) Cb[(long)g * sCbg + mrow * ldcb + n] = f2bf(v);
                }
            }
        }
    }
}

// ---------------------------------------------------------------------------
extern "C" void kernel_launch(void* const* d_in, const int* in_sizes, int n_in,
                              void* d_out, int out_size, void* d_ws, size_t ws_size,
                              hipStream_t stream) {
    const int B = 4096, S = 256, D = 128, NA = 32, CD = 512;

    const float* state   = (const float*)d_in[0];
    const float* enc_w1  = (const float*)d_in[1];
    const float* enc_b1  = (const float*)d_in[2];
    const float* enc_wh  = (const float*)d_in[3];
    const float* enc_bh  = (const float*)d_in[4];
    const float* enc_wo  = (const float*)d_in[5];
    const float* enc_bo  = (const float*)d_in[6];
    const float *agg_w1[3], *agg_b1[3], *agg_wh[3], *agg_bh[3], *agg_wo[3], *agg_bo[3];
    for (int l = 0; l < 3; ++l) {
        agg_w1[l] = (const float*)d_in[7 + 6 * l + 0];
        agg_b1[l] = (const float*)d_in[7 + 6 * l + 1];
        agg_wh[l] = (const float*)d_in[7 + 6 * l + 2];
        agg_bh[l] = (const float*)d_in[7 + 6 * l + 3];
        agg_wo[l] = (const float*)d_in[7 + 6 * l + 4];
        agg_bo[l] = (const float*)d_in[7 + 6 * l + 5];
    }
    const float* head_w1 = (const float*)d_in[25];
    const float* head_b1 = (const float*)d_in[26];
    const float* head_wh = (const float*)d_in[27];
    const float* head_bh = (const float*)d_in[28];
    const float* head_wo = (const float*)d_in[29];
    const float* head_bo = (const float*)d_in[30];

    float* out    = (float*)d_out;               // embeds [B][85][128] fp32
    float* action = out + (long)B * 85 * D;      // [B][32] fp32

    // ---- carve workspace (bf16 elements)
    char* wsp = (char*)d_ws;
    auto carve = [&](long elems) {
        u16* p = (u16*)wsp;
        wsp += ((elems * 2 + 255) / 256) * 256;
        return p;
    };
    u16* enc_w1t = carve(64L * 128 * 256);
    u16* enc_wht = carve(64L * 128 * 128);
    u16* enc_wot = carve(64L * 128 * 128);
    u16 *agg_w1t[3], *agg_wht[3], *agg_wot[3];
    const int LN[3] = {16, 4, 1};
    for (int l = 0; l < 3; ++l) {
        agg_w1t[l] = carve((long)LN[l] * 512 * 512);
        agg_wht[l] = carve((long)LN[l] * 512 * 512);
        agg_wot[l] = carve((long)LN[l] * 128 * 512);
    }
    u16* head_w1t = carve(128L * 128);
    u16* head_wht = carve(128L * 128);
    u16* head_wot = carve(32L * 128);
    u16* stateB = carve((long)B * S);            // bf16 state
    u16* bufA   = carve(33554432L);              // bf16 activation mirrors
    u16* bufB   = carve(33554432L);

    // ---- build merged transpose/convert table (one launch)
    TTab tab = {};
    int nj = 0, base = 0;
    auto addT = [&](const float* s, u16* d, int G, int K, int N) {
        int tpg = (K / 32) * (N / 32);
        tab.j[nj] = {s, d, K, N, tpg, base, 0};
        base += G * tpg; ++nj;
    };
    auto addC = [&](const float* s, u16* d, long elems) {
        tab.j[nj] = {s, d, 0, 0, 0, base, 1};
        base += (int)(elems / 1024); ++nj;
    };
    addT(enc_w1, enc_w1t, 64, 256, 128);
    addT(enc_wh, enc_wht, 64, 128, 128);
    addT(enc_wo, enc_wot, 64, 128, 128);
    for (int l = 0; l < 3; ++l) {
        addT(agg_w1[l], agg_w1t[l], LN[l], 512, 512);
        addT(agg_wh[l], agg_wht[l], LN[l], 512, 512);
        addT(agg_wo[l], agg_wot[l], LN[l], 512, 128);
    }
    addT(head_w1, head_w1t, 1, 128, 128);
    addT(head_wh, head_wht, 1, 128, 128);
    addT(head_wo, head_wot, 1, 128, 32);
    addC(state, stateB, (long)B * S);
    transpose_multi<<<base, 256, 0, stream>>>(tab, nj);

    const int LD = 85 * D;   // 10880
    const int MB64 = B / 64; // 64 m-blocks of 64 rows

    // encoders: fused chain, out fp32 embeds[:,0:64,:] + bf16 mirror [B][64D]
    fnn_chain128<<<MB64 * 64, 256, 0, stream>>>(
        64, stateB, 0, S, 256,
        enc_w1t, enc_b1, enc_wht, enc_bh, enc_wot, enc_bo, 128, 0,
        out, D, LD, bufA, D, 64 * D);

    // agg level 0: X = enc mirror [B][64D]; out t=64.. + mirror [B][16D]
    fnn_chain512<<<MB64 * 16, 512, 0, stream>>>(
        16, bufA, 512, 64 * D,
        agg_w1t[0], agg_b1[0], agg_wht[0], agg_bh[0], agg_wot[0], agg_bo[0],
        out + 64L * D, D, LD, bufB, D, 16 * D);

    // agg level 1: X = [B][16D]; out t=80.. + mirror [B][4D]
    fnn_chain512<<<MB64 * 4, 512, 0, stream>>>(
        4, bufB, 512, 16 * D,
        agg_w1t[1], agg_b1[1], agg_wht[1], agg_bh[1], agg_wot[1], agg_bo[1],
        out + 80L * D, D, LD, bufA, D, 4 * D);

    // agg level 2 (root): X = [B][4D]; out t=84 + mirror [B][D]
    fnn_chain512<<<MB64, 512, 0, stream>>>(
        1, bufA, 0, 4 * D,
        agg_w1t[2], agg_b1[2], agg_wht[2], agg_bh[2], agg_wot[2], agg_bo[2],
        out + 84L * D, D, LD, bufB, 0, D);

    // head: fused chain, X = root mirror [B][D], tanh, Do=32
    fnn_chain128<<<MB64, 256, 0, stream>>>(
        1, bufB, 0, D, 128,
        head_w1t, head_b1, head_wht, head_bh, head_wot, head_bo, 32, 2,
        action, 0, NA, nullptr, 0, 0);
}

// Round 5
// 625.805 us; speedup vs baseline: 1.2020x; 1.0358x over previous
//
#include <hip/hip_runtime.h>
#include <math.h>

typedef unsigned short u16;
typedef __bf16 bf16x8 __attribute__((ext_vector_type(8)));
typedef float  f32x4  __attribute__((ext_vector_type(4)));

__device__ __forceinline__ u16 f2bf(float f) {
    unsigned int u = __float_as_uint(f);
    u = (u + 0x7FFFu + ((u >> 16) & 1u)) >> 16;   // RNE
    return (u16)u;
}

// async global->LDS, 16B/lane; LDS dest must be lane-linear within each wave
__device__ __forceinline__ void gload16(const u16* g, u16* l) {
    __builtin_amdgcn_global_load_lds(
        (const __attribute__((address_space(1))) void*)g,
        (__attribute__((address_space(3))) void*)l, 16, 0, 0);
}

// h-LDS XOR swizzle (chain128 only): element index ^= (row&7)<<3.
__device__ __forceinline__ int hswz(int row, int col, int ld) {
    return (row * ld + col) ^ ((row & 7) << 3);
}

// XCD-pinned block decode: consecutive flat blockIdx round-robin the 8 XCDs,
// so fixing g per (bid&7) makes each group's weights L2-resident on one XCD.
// Bijective for n_g multiple of 8 (branch 1) or divisor of 8 (branch 2).
__device__ __forceinline__ void xcd_decode(int bid, int n_g, int& mb, int& g) {
    int xcd = bid & 7, j = bid >> 3;
    if (n_g >= 8) {
        int gpx = n_g >> 3;                 // groups per XCD
        g  = xcd * gpx + (j % gpx);
        mb = j / gpx;
    } else {
        int xpg = 8 / n_g;                  // XCDs per group
        g  = xcd / xpg;
        mb = j * xpg + (xcd % xpg);
    }
}

// ---------------------------------------------------------------------------
// Merged weight transpose+convert (mode 0: fp32 [G][K][N] -> bf16 [G][N][K])
// and linear fp32->bf16 convert (mode 1, 1024 elems/tile). One launch.
// ---------------------------------------------------------------------------
struct TJob { const float* src; u16* dst; int K, N, tpg, gbase, mode; };
struct TTab { TJob j[16]; };

__global__ void transpose_multi(TTab tab, int njobs) {
    __shared__ u16 tile[32][33];
    int bid = blockIdx.x;
    int ji = 0;
#pragma unroll 1
    for (int t = 1; t < njobs; ++t)
        if (bid >= tab.j[t].gbase) ji = t;
    TJob jb = tab.j[ji];
    int t = bid - jb.gbase;
    if (jb.mode == 1) {                       // linear convert
        long off = (long)t * 1024 + threadIdx.x * 4;
        float4 x = *(const float4*)(jb.src + off);
        ushort4 o;
        o.x = f2bf(x.x); o.y = f2bf(x.y); o.z = f2bf(x.z); o.w = f2bf(x.w);
        *(ushort4*)(jb.dst + off) = o;
        return;
    }
    int g = t / jb.tpg, r = t % jb.tpg;
    int nt = jb.N >> 5;
    int k0 = (r / nt) * 32, n0 = (r % nt) * 32;
    const float* s = jb.src + (long)g * jb.K * jb.N;
    u16* d = jb.dst + (long)g * jb.K * jb.N;
    int tx = threadIdx.x & 31, ty = threadIdx.x >> 5;
#pragma unroll
    for (int rr = ty; rr < 32; rr += 8)
        tile[rr][tx] = f2bf(s[(long)(k0 + rr) * jb.N + n0 + tx]);
    __syncthreads();
#pragma unroll
    for (int rr = ty; rr < 32; rr += 8)
        d[(long)(n0 + rr) * jb.K + k0 + tx] = tile[tx][rr];
}

// ---------------------------------------------------------------------------
// Fused 3-layer FNN chain, hidden width 128 (encoders, head).
// Block = 64 rows x 128 cols, 4 waves (2Mx2N, wave tile 32x64).
// A panel (64 x K1) preloaded to registers (areg[KT1]) -> L1 K-loop stages A
// via ds_write (depth-KT1 HBM pipeline); W via gload16 double-buffer.
// LDS: As 8KB + Bs 16KB + h 16KB = 40KB -> 4 blocks/CU (16 waves/CU).
// grid: 1-D (n_mb * n_g), XCD-pinned decode.
// ---------------------------------------------------------------------------
template<int KT1>
__global__ __launch_bounds__(256, 4)
void fnn_chain128(int n_g,
                  const u16* __restrict__ X, long sXg, int ldx,
                  const u16* __restrict__ W1t, const float* __restrict__ b1,
                  const u16* __restrict__ Wht, const float* __restrict__ bh,
                  const u16* __restrict__ Wot, const float* __restrict__ bo,
                  int Do, int act3,
                  float* __restrict__ Cf, long sCfg, int ldcf,
                  u16* __restrict__ Cb, long sCbg, int ldcb)
{
    const int K1 = KT1 * 32;
    __shared__ __align__(16) u16 As[2][64 * 32];
    __shared__ __align__(16) u16 Bs[2][128 * 32];
    __shared__ __align__(16) u16 h[64 * 128];   // XOR-swizzled

    int mb, g;
    xcd_decode(blockIdx.x, n_g, mb, g);
    const int m0  = mb * 64;
    const int tid = threadIdx.x;
    const int lane = tid & 63, wv = tid >> 6;
    const int wm = wv & 1, wn = wv >> 1;
    const int lr = lane & 15, lq = lane >> 4;
    const int arow = tid >> 2, akc = (tid & 3) * 8;   // staging granule map

    const u16* a_src = X + (long)g * sXg + (long)(m0 + arow) * ldx + akc;
    const u16* w1r   = W1t + (long)g * 128 * K1 + (long)arow * K1 + akc;
    const u16* whr   = Wht + (long)g * 128 * 128 + (long)arow * 128 + akc;

    // ---- A panel -> registers (depth-KT1 pipeline over HBM/L2 latency)
    bf16x8 areg[KT1];
#pragma unroll
    for (int kt = 0; kt < KT1; ++kt)
        areg[kt] = *(const bf16x8*)(a_src + kt * 32);

    const f32x4 z4 = {0.f, 0.f, 0.f, 0.f};
    f32x4 acc[2][4];
#pragma unroll
    for (int i = 0; i < 2; ++i)
#pragma unroll
        for (int j = 0; j < 4; ++j) acc[i][j] = z4;

    // ---------------- L1: X @ W1 (K=K1)
    auto stageW1 = [&](int buf, int k0) {
        gload16(w1r + k0,                 &Bs[buf][arow * 32 + akc]);
        gload16(w1r + (long)64 * K1 + k0, &Bs[buf][(arow + 64) * 32 + akc]);
    };
    stageW1(0, 0);
    *(bf16x8*)&As[0][arow * 32 + akc] = areg[0];
    __syncthreads();
#pragma unroll
    for (int kt = 0; kt < KT1; ++kt) {
        const int cur = kt & 1;
        if (kt + 1 < KT1) {
            stageW1(cur ^ 1, (kt + 1) * 32);
            *(bf16x8*)&As[cur ^ 1][arow * 32 + akc] = areg[kt + 1];
        }
        bf16x8 af[2], bw[4];
#pragma unroll
        for (int i = 0; i < 2; ++i)
            af[i] = *(const bf16x8*)&As[cur][(wm * 32 + i * 16 + lr) * 32 + lq * 8];
#pragma unroll
        for (int j = 0; j < 4; ++j)
            bw[j] = *(const bf16x8*)&Bs[cur][(wn * 64 + j * 16 + lr) * 32 + lq * 8];
#pragma unroll
        for (int i = 0; i < 2; ++i)
#pragma unroll
            for (int j = 0; j < 4; ++j)
                acc[i][j] = __builtin_amdgcn_mfma_f32_16x16x32_bf16(
                    af[i], bw[j], acc[i][j], 0, 0, 0);
        __syncthreads();
    }
    {   // bias + relu -> h (swizzled)
        const float* bg = b1 + (long)g * 128;
#pragma unroll
        for (int j = 0; j < 4; ++j) {
            int n = wn * 64 + j * 16 + lr;
            float bb = bg[n];
#pragma unroll
            for (int i = 0; i < 2; ++i) {
                int mb2 = wm * 32 + i * 16 + lq * 4;
#pragma unroll
                for (int r = 0; r < 4; ++r)
                    h[hswz(mb2 + r, n, 128)] = f2bf(fmaxf(acc[i][j][r] + bb, 0.f));
            }
        }
    }

    // ---------------- L2: h @ Wh (K=128)
#pragma unroll
    for (int i = 0; i < 2; ++i)
#pragma unroll
        for (int j = 0; j < 4; ++j) acc[i][j] = z4;
    auto stage2 = [&](int buf, int k0) {
        gload16(whr + k0,                  &Bs[buf][arow * 32 + akc]);
        gload16(whr + (long)64 * 128 + k0, &Bs[buf][(arow + 64) * 32 + akc]);
    };
    stage2(0, 0);
    __syncthreads();
    for (int kt = 0; kt < 4; ++kt) {
        int cur = kt & 1;
        if (kt + 1 < 4) stage2(cur ^ 1, (kt + 1) * 32);
        bf16x8 af[2], bw[4];
#pragma unroll
        for (int i = 0; i < 2; ++i) {
            int row = wm * 32 + i * 16 + lr;
            af[i] = *(const bf16x8*)&h[hswz(row, kt * 32 + lq * 8, 128)];
        }
#pragma unroll
        for (int j = 0; j < 4; ++j)
            bw[j] = *(const bf16x8*)&Bs[cur][(wn * 64 + j * 16 + lr) * 32 + lq * 8];
#pragma unroll
        for (int i = 0; i < 2; ++i)
#pragma unroll
            for (int j = 0; j < 4; ++j)
                acc[i][j] = __builtin_amdgcn_mfma_f32_16x16x32_bf16(
                    af[i], bw[j], acc[i][j], 0, 0, 0);
        __syncthreads();
    }
    {   // bias + relu -> h (in place; all reads drained at final barrier)
        const float* bg = bh + (long)g * 128;
#pragma unroll
        for (int j = 0; j < 4; ++j) {
            int n = wn * 64 + j * 16 + lr;
            float bb = bg[n];
#pragma unroll
            for (int i = 0; i < 2; ++i) {
                int mb2 = wm * 32 + i * 16 + lq * 4;
#pragma unroll
                for (int r = 0; r < 4; ++r)
                    h[hswz(mb2 + r, n, 128)] = f2bf(fmaxf(acc[i][j][r] + bb, 0.f));
            }
        }
    }

    // ---------------- L3: h @ Wo (K=128, Do cols)
#pragma unroll
    for (int i = 0; i < 2; ++i)
#pragma unroll
        for (int j = 0; j < 4; ++j) acc[i][j] = z4;
    const int nr0 = (arow < Do) ? arow : Do - 1;          // clamp (Do=32 tail)
    const int nr1 = (arow + 64 < Do) ? arow + 64 : Do - 1;
    const u16* wor0 = Wot + (long)g * Do * 128 + (long)nr0 * 128 + akc;
    const u16* wor1 = Wot + (long)g * Do * 128 + (long)nr1 * 128 + akc;
    auto stage3 = [&](int buf, int k0) {
        gload16(wor0 + k0, &Bs[buf][arow * 32 + akc]);
        gload16(wor1 + k0, &Bs[buf][(arow + 64) * 32 + akc]);
    };
    stage3(0, 0);
    __syncthreads();
    for (int kt = 0; kt < 4; ++kt) {
        int cur = kt & 1;
        if (kt + 1 < 4) stage3(cur ^ 1, (kt + 1) * 32);
        bf16x8 af[2], bw[4];
#pragma unroll
        for (int i = 0; i < 2; ++i) {
            int row = wm * 32 + i * 16 + lr;
            af[i] = *(const bf16x8*)&h[hswz(row, kt * 32 + lq * 8, 128)];
        }
#pragma unroll
        for (int j = 0; j < 4; ++j)
            bw[j] = *(const bf16x8*)&Bs[cur][(wn * 64 + j * 16 + lr) * 32 + lq * 8];
#pragma unroll
        for (int i = 0; i < 2; ++i)
#pragma unroll
            for (int j = 0; j < 4; ++j)
                acc[i][j] = __builtin_amdgcn_mfma_f32_16x16x32_bf16(
                    af[i], bw[j], acc[i][j], 0, 0, 0);
        __syncthreads();
    }
    {   // bias + act3 -> Cf (+Cb mirror)
        const float* bg = bo + (long)g * Do;
#pragma unroll
        for (int j = 0; j < 4; ++j) {
            int n = wn * 64 + j * 16 + lr;
            if (n >= Do) continue;
            float bb = bg[n];
#pragma unroll
            for (int i = 0; i < 2; ++i) {
                int mb2 = wm * 32 + i * 16 + lq * 4;
#pragma unroll
                for (int r = 0; r < 4; ++r) {
                    float v = acc[i][j][r] + bb;
                    if (act3 == 2) v = tanhf(v);
                    long mrow = m0 + mb2 + r;
                    Cf[(long)g * sCfg + mrow * ldcf + n] = v;
                    if (Cb) Cb[(long)g * sCbg + mrow * ldcb + n] = f2bf(v);
                }
            }
        }
    }
}

// ---------------------------------------------------------------------------
// Fused 3-layer FNN chain, hidden width 512 (aggregators). K=512 all layers.
// Block = 64 rows x 512 cols, 8 waves (wave tile 64x64 for L1/L2 = 16
// MFMA/wave/K-step). A panel (64x512=64KB) preloaded to registers by the
// 256 staging threads (areg[16], 32 VGPR) -> L1 stages A via ds_write
// (depth-16 HBM pipeline). W via gload16 double-buffer (L2-resident via
// XCD pinning). h[64][536] in LDS. LDS 139KB -> 1 block/CU.
// grid: 1-D (n_mb * n_g), XCD-pinned decode.
// ---------------------------------------------------------------------------
__global__ __launch_bounds__(512, 2)
void fnn_chain512(int n_g,
                  const u16* __restrict__ X, long sXg, int ldx,
                  const u16* __restrict__ W1t, const float* __restrict__ b1,
                  const u16* __restrict__ Wht, const float* __restrict__ bh,
                  const u16* __restrict__ Wot, const float* __restrict__ bo,
                  float* __restrict__ Cf, long sCfg, int ldcf,
                  u16* __restrict__ Cb, long sCbg, int ldcb)
{
    __shared__ __align__(16) u16 As[2][64 * 32];
    __shared__ __align__(16) u16 Bs[2][512 * 32];
    __shared__ __align__(16) u16 h[64 * 536];

    int mb, g;
    xcd_decode(blockIdx.x, n_g, mb, g);
    const int m0  = mb * 64;
    const int tid = threadIdx.x;
    const int lane = tid & 63, wv = tid >> 6;     // wv 0..7
    const int lr = lane & 15, lq = lane >> 4;
    const int row0 = tid >> 2, c8 = (tid & 3) * 8;  // row0 0..127

    const u16* a_src = X + (long)g * sXg + (long)(m0 + row0) * ldx + c8; // tid<256
    const u16* w1r = W1t + (long)g * 512 * 512 + (long)row0 * 512 + c8;
    const u16* whr = Wht + (long)g * 512 * 512 + (long)row0 * 512 + c8;
    const u16* wor = Wot + (long)g * 128 * 512 + (long)row0 * 512 + c8;

    // ---- A panel -> registers (staging threads only; depth-16 pipeline)
    bf16x8 areg[16];
    if (tid < 256) {
#pragma unroll
        for (int kt = 0; kt < 16; ++kt)
            areg[kt] = *(const bf16x8*)(a_src + kt * 32);
    }

    const f32x4 z4 = {0.f, 0.f, 0.f, 0.f};
    f32x4 acc[4][4];
#pragma unroll
    for (int i = 0; i < 4; ++i)
#pragma unroll
        for (int j = 0; j < 4; ++j) acc[i][j] = z4;

    // ---------------- L1: X @ W1  (K=512, 16 steps, fully unrolled)
    auto stageW1 = [&](int buf, int k0) {
#pragma unroll
        for (int r = 0; r < 4; ++r)
            gload16(w1r + (long)(128 * r) * 512 + k0,
                    &Bs[buf][(row0 + 128 * r) * 32 + c8]);
    };
    stageW1(0, 0);
    if (tid < 256) *(bf16x8*)&As[0][row0 * 32 + c8] = areg[0];
    __syncthreads();
#pragma unroll
    for (int kt = 0; kt < 16; ++kt) {
        const int cur = kt & 1;
        if (kt + 1 < 16) {
            stageW1(cur ^ 1, (kt + 1) * 32);
            if (tid < 256) *(bf16x8*)&As[cur ^ 1][row0 * 32 + c8] = areg[kt + 1];
        }
        bf16x8 af[4], bw[4];
#pragma unroll
        for (int i = 0; i < 4; ++i)
            af[i] = *(const bf16x8*)&As[cur][(i * 16 + lr) * 32 + lq * 8];
#pragma unroll
        for (int j = 0; j < 4; ++j)
            bw[j] = *(const bf16x8*)&Bs[cur][(wv * 64 + j * 16 + lr) * 32 + lq * 8];
#pragma unroll
        for (int i = 0; i < 4; ++i)
#pragma unroll
            for (int j = 0; j < 4; ++j)
                acc[i][j] = __builtin_amdgcn_mfma_f32_16x16x32_bf16(
                    af[i], bw[j], acc[i][j], 0, 0, 0);
        __syncthreads();
    }
    {   // b1 + relu -> h
        const float* bg = b1 + (long)g * 512;
#pragma unroll
        for (int j = 0; j < 4; ++j) {
            int n = wv * 64 + j * 16 + lr;
            float bb = bg[n];
#pragma unroll
            for (int i = 0; i < 4; ++i) {
                int mb2 = i * 16 + lq * 4;
#pragma unroll
                for (int r = 0; r < 4; ++r)
                    h[(mb2 + r) * 536 + n] = f2bf(fmaxf(acc[i][j][r] + bb, 0.f));
            }
        }
    }

    // ---------------- L2: h @ Wh (K=512)
#pragma unroll
    for (int i = 0; i < 4; ++i)
#pragma unroll
        for (int j = 0; j < 4; ++j) acc[i][j] = z4;
    auto stage2 = [&](int buf, int k0) {
#pragma unroll
        for (int r = 0; r < 4; ++r)
            gload16(whr + (long)(128 * r) * 512 + k0,
                    &Bs[buf][(row0 + 128 * r) * 32 + c8]);
    };
    stage2(0, 0);
    __syncthreads();
    for (int kt = 0; kt < 16; ++kt) {
        int cur = kt & 1;
        if (kt + 1 < 16) stage2(cur ^ 1, (kt + 1) * 32);
        bf16x8 af[4], bw[4];
#pragma unroll
        for (int i = 0; i < 4; ++i)
            af[i] = *(const bf16x8*)&h[(i * 16 + lr) * 536 + kt * 32 + lq * 8];
#pragma unroll
        for (int j = 0; j < 4; ++j)
            bw[j] = *(const bf16x8*)&Bs[cur][(wv * 64 + j * 16 + lr) * 32 + lq * 8];
#pragma unroll
        for (int i = 0; i < 4; ++i)
#pragma unroll
            for (int j = 0; j < 4; ++j)
                acc[i][j] = __builtin_amdgcn_mfma_f32_16x16x32_bf16(
                    af[i], bw[j], acc[i][j], 0, 0, 0);
        __syncthreads();
    }
    {   // bh + relu -> h (in place)
        const float* bg = bh + (long)g * 512;
#pragma unroll
        for (int j = 0; j < 4; ++j) {
            int n = wv * 64 + j * 16 + lr;
            float bb = bg[n];
#pragma unroll
            for (int i = 0; i < 4; ++i) {
                int mb2 = i * 16 + lq * 4;
#pragma unroll
                for (int r = 0; r < 4; ++r)
                    h[(mb2 + r) * 536 + n] = f2bf(fmaxf(acc[i][j][r] + bb, 0.f));
            }
        }
    }

    // ---------------- L3: h @ Wo (K=512, Do=128); 8 waves = 2Mx4N
    const int wm3 = wv & 1, wn3 = wv >> 1;   // wn3 0..3
    f32x4 a2[2][2];
#pragma unroll
    for (int i = 0; i < 2; ++i)
#pragma unroll
        for (int j = 0; j < 2; ++j) a2[i][j] = z4;
    auto stage3 = [&](int buf, int k0) {
        gload16(wor + k0, &Bs[buf][row0 * 32 + c8]);   // 128 rows, one granule
    };
    stage3(0, 0);
    __syncthreads();
    for (int kt = 0; kt < 16; ++kt) {
        int cur = kt & 1;
        if (kt + 1 < 16) stage3(cur ^ 1, (kt + 1) * 32);
        bf16x8 af2[2], bw2[2];
#pragma unroll
        for (int i = 0; i < 2; ++i)
            af2[i] = *(const bf16x8*)&h[(wm3 * 32 + i * 16 + lr) * 536 + kt * 32 + lq * 8];
#pragma unroll
        for (int j = 0; j < 2; ++j)
            bw2[j] = *(const bf16x8*)&Bs[cur][(wn3 * 32 + j * 16 + lr) * 32 + lq * 8];
#pragma unroll
        for (int i = 0; i < 2; ++i)
#pragma unroll
            for (int j = 0; j < 2; ++j)
                a2[i][j] = __builtin_amdgcn_mfma_f32_16x16x32_bf16(
                    af2[i], bw2[j], a2[i][j], 0, 0, 0);
        __syncthreads();
    }
    {   // bo -> Cf (+Cb mirror), no activation
        const float* bg = bo + (long)g * 128;
#pragma unroll
        for (int j = 0; j < 2; ++j) {
            int n = wn3 * 32 + j * 16 + lr;
            float bb = bg[n];
#pragma unroll
            for (int i = 0; i < 2; ++i) {
                int mb2 = wm3 * 32 + i * 16 + lq * 4;
#pragma unroll
                for (int r = 0; r < 4; ++r) {
                    float v = a2[i][j][r] + bb;
                    long mrow = m0 + mb2 + r;
                    Cf[(long)g * sCfg + mrow * ldcf + n] = v;
                    if (Cb) Cb[(long)g * sCbg + mrow * ldcb + n] = f2bf(v);
                }
            }
        }
    }
}

// ---------------------------------------------------------------------------
extern "C" void kernel_launch(void* const* d_in, const int* in_sizes, int n_in,
                              void* d_out, int out_size, void* d_ws, size_t ws_size,
                              hipStream_t stream) {
    const int B = 4096, S = 256, D = 128, NA = 32, CD = 512;

    const float* state   = (const float*)d_in[0];
    const float* enc_w1  = (const float*)d_in[1];
    const float* enc_b1  = (const float*)d_in[2];
    const float* enc_wh  = (const float*)d_in[3];
    const float* enc_bh  = (const float*)d_in[4];
    const float* enc_wo  = (const float*)d_in[5];
    const float* enc_bo  = (const float*)d_in[6];
    const float *agg_w1[3], *agg_b1[3], *agg_wh[3], *agg_bh[3], *agg_wo[3], *agg_bo[3];
    for (int l = 0; l < 3; ++l) {
        agg_w1[l] = (const float*)d_in[7 + 6 * l + 0];
        agg_b1[l] = (const float*)d_in[7 + 6 * l + 1];
        agg_wh[l] = (const float*)d_in[7 + 6 * l + 2];
        agg_bh[l] = (const float*)d_in[7 + 6 * l + 3];
        agg_wo[l] = (const float*)d_in[7 + 6 * l + 4];
        agg_bo[l] = (const float*)d_in[7 + 6 * l + 5];
    }
    const float* head_w1 = (const float*)d_in[25];
    const float* head_b1 = (const float*)d_in[26];
    const float* head_wh = (const float*)d_in[27];
    const float* head_bh = (const float*)d_in[28];
    const float* head_wo = (const float*)d_in[29];
    const float* head_bo = (const float*)d_in[30];

    float* out    = (float*)d_out;               // embeds [B][85][128] fp32
    float* action = out + (long)B * 85 * D;      // [B][32] fp32

    // ---- carve workspace (bf16 elements)
    char* wsp = (char*)d_ws;
    auto carve = [&](long elems) {
        u16* p = (u16*)wsp;
        wsp += ((elems * 2 + 255) / 256) * 256;
        return p;
    };
    u16* enc_w1t = carve(64L * 128 * 256);
    u16* enc_wht = carve(64L * 128 * 128);
    u16* enc_wot = carve(64L * 128 * 128);
    u16 *agg_w1t[3], *agg_wht[3], *agg_wot[3];
    const int LN[3] = {16, 4, 1};
    for (int l = 0; l < 3; ++l) {
        agg_w1t[l] = carve((long)LN[l] * 512 * 512);
        agg_wht[l] = carve((long)LN[l] * 512 * 512);
        agg_wot[l] = carve((long)LN[l] * 128 * 512);
    }
    u16* head_w1t = carve(128L * 128);
    u16* head_wht = carve(128L * 128);
    u16* head_wot = carve(32L * 128);
    u16* stateB = carve((long)B * S);            // bf16 state
    u16* bufA   = carve(33554432L);              // bf16 activation mirrors
    u16* bufB   = carve(33554432L);

    // ---- build merged transpose/convert table (one launch)
    TTab tab = {};
    int nj = 0, base = 0;
    auto addT = [&](const float* s, u16* d, int G, int K, int N) {
        int tpg = (K / 32) * (N / 32);
        tab.j[nj] = {s, d, K, N, tpg, base, 0};
        base += G * tpg; ++nj;
    };
    auto addC = [&](const float* s, u16* d, long elems) {
        tab.j[nj] = {s, d, 0, 0, 0, base, 1};
        base += (int)(elems / 1024); ++nj;
    };
    addT(enc_w1, enc_w1t, 64, 256, 128);
    addT(enc_wh, enc_wht, 64, 128, 128);
    addT(enc_wo, enc_wot, 64, 128, 128);
    for (int l = 0; l < 3; ++l) {
        addT(agg_w1[l], agg_w1t[l], LN[l], 512, 512);
        addT(agg_wh[l], agg_wht[l], LN[l], 512, 512);
        addT(agg_wo[l], agg_wot[l], LN[l], 512, 128);
    }
    addT(head_w1, head_w1t, 1, 128, 128);
    addT(head_wh, head_wht, 1, 128, 128);
    addT(head_wo, head_wot, 1, 128, 32);
    addC(state, stateB, (long)B * S);
    transpose_multi<<<base, 256, 0, stream>>>(tab, nj);

    const int LD = 85 * D;   // 10880
    const int MB64 = B / 64; // 64 m-blocks of 64 rows

    // encoders: fused chain, out fp32 embeds[:,0:64,:] + bf16 mirror [B][64D]
    fnn_chain128<8><<<MB64 * 64, 256, 0, stream>>>(
        64, stateB, 0, S,
        enc_w1t, enc_b1, enc_wht, enc_bh, enc_wot, enc_bo, 128, 0,
        out, D, LD, bufA, D, 64 * D);

    // agg level 0: X = enc mirror [B][64D]; out t=64.. + mirror [B][16D]
    fnn_chain512<<<MB64 * 16, 512, 0, stream>>>(
        16, bufA, 512, 64 * D,
        agg_w1t[0], agg_b1[0], agg_wht[0], agg_bh[0], agg_wot[0], agg_bo[0],
        out + 64L * D, D, LD, bufB, D, 16 * D);

    // agg level 1: X = [B][16D]; out t=80.. + mirror [B][4D]
    fnn_chain512<<<MB64 * 4, 512, 0, stream>>>(
        4, bufB, 512, 16 * D,
        agg_w1t[1], agg_b1[1], agg_wht[1], agg_bh[1], agg_wot[1], agg_bo[1],
        out + 80L * D, D, LD, bufA, D, 4 * D);

    // agg level 2 (root): X = [B][4D]; out t=84 + mirror [B][D]
    fnn_chain512<<<MB64, 512, 0, stream>>>(
        1, bufA, 0, 4 * D,
        agg_w1t[2], agg_b1[2], agg_wht[2], agg_bh[2], agg_wot[2], agg_bo[2],
        out + 84L * D, D, LD, bufB, 0, D);

    // head: fused chain, X = root mirror [B][D], tanh, Do=32
    fnn_chain128<4><<<MB64, 256, 0, stream>>>(
        1, bufB, 0, D,
        head_w1t, head_b1, head_wht, head_bh, head_wot, head_bo, 32, 2,
        action, 0, NA, nullptr, 0, 0);
}